// Round 6
// baseline (355.034 us; speedup 1.0000x reference)
//
#include <hip/hip_runtime.h>
#include <hip/hip_bf16.h>
#include <stdint.h>

// Problem constants (fixed by the reference setup_inputs)
#define BATCH  16384
#define D_IN   1024
#define M_HID  4096
#define R_LORA 16
#define SCALING 2.0f   // ALPHA/R = 32/16

// R11: R10's capacity-guaranteed L2 pinning was a NULL (MfmaUtil 31% vs R5's
// 40%) => the wall is the per-CU vector-load path (~21-24 B/cyc/CU measured
// identically in R5/R7/R10), not L2/LLC aggregate BW. Only lever: halve wf
// bytes per CU by doubling rows/block to 128 (2 KB of wf now feeds 8 MFMA).
// x (128x1024 bf16 = 256 KB) can't fit LDS -> split K in HALVES (128 KB tile)
// and ZIGZAG khalf order across the 4 col-passes so only 5 stagings total
// (R6's fatal flaw was 16). acc[4][2]=128 f32 -> AGPRs (R6 precedent: same
// shape, VGPR_Count 128, no spill). Inner body = proven R5 loop with af[4],
// depth-4 wf ring, same 0-conflict XOR bank pattern. Output: out=b2 init in
// k_wprep + 2 atomicAdds/row (proven harmless in R8/R10).

typedef __bf16 bf16x8 __attribute__((ext_vector_type(8)));
typedef float  f32x16 __attribute__((ext_vector_type(16)));

__device__ __forceinline__ unsigned f2bf(float f) {
    union { float f; unsigned u; } c; c.f = f;
    unsigned u = c.u;
    return ((u + 0x7FFFu + ((u >> 16) & 1u)) >> 16);
}

// ---------------- prep v3: W_eff -> fragment-ordered bf16 ----------------
// Layout (shorts): n32*32768 + c*256 + rl*8 holds W_eff[n32*32+rl][c*8 .. c*8+8).
// Also initializes out = b2[0] (atomicAdd target).
__global__ __launch_bounds__(512) void k_wprep(
    const float* __restrict__ W0, const float* __restrict__ A,
    const float* __restrict__ Bl, const float* __restrict__ b2,
    unsigned short* __restrict__ wb, float* __restrict__ out)
{
    __shared__ float Bs[512];                     // 32 rows x 16 r, pre-scaled
    const int tid   = threadIdx.x;
    const int n32   = blockIdx.x >> 1;            // 0..127
    const int chalf = blockIdx.x & 1;
    const int col0  = chalf * 512;

    {   // out = b2 broadcast (first 32 blocks cover all 16384 rows)
        int oid = blockIdx.x * 512 + tid;
        if (oid < BATCH) out[oid] = b2[0];
    }

    Bs[tid] = SCALING * Bl[n32 * 512 + tid];
    __syncthreads();

    const int lane = tid & 63;
    const int w    = tid >> 6;                    // 0..7
    const float* a_base = A + col0 + lane * 8;

#pragma unroll
    for (int j = 0; j < 4; ++j) {
        const int row = j * 8 + w;                // 0..31
        const int n   = n32 * 32 + row;
        const float* p = W0 + (size_t)n * D_IN + col0 + lane * 8;
        float4 v0 = *(const float4*)(p);
        float4 v1 = *(const float4*)(p + 4);
        const float* bsr = &Bs[row * 16];
#pragma unroll
        for (int r = 0; r < R_LORA; ++r) {
            float s = bsr[r];
            const float* ap = a_base + r * D_IN;
            float4 a0 = *(const float4*)(ap);
            float4 a1 = *(const float4*)(ap + 4);
            v0.x += s * a0.x; v0.y += s * a0.y; v0.z += s * a0.z; v0.w += s * a0.w;
            v1.x += s * a1.x; v1.y += s * a1.y; v1.z += s * a1.z; v1.w += s * a1.w;
        }
        uint4 o;
        o.x = f2bf(v0.x) | (f2bf(v0.y) << 16);
        o.y = f2bf(v0.z) | (f2bf(v0.w) << 16);
        o.z = f2bf(v1.x) | (f2bf(v1.y) << 16);
        o.w = f2bf(v1.z) | (f2bf(v1.w) << 16);
        *(uint4*)(&wb[(size_t)n32 * 32768 + (size_t)(chalf * 64 + lane) * 256 + row * 8]) = o;
    }
}

// ---------------- main fused kernel: 128 rows x 2048 hidden, K zigzag ----------
// As (shorts): r*512 + ((slot ^ (r&31))<<3) holds x_bf16[row0+r][k*512 + slot*8
// .. +8) -- same XOR bank pattern that measured SQ_LDS_BANK_CONFLICT = 0.
__global__ __launch_bounds__(512, 2) void k_strip(
    const float* __restrict__ xf, const unsigned short* __restrict__ wb,
    const float* __restrict__ b0, const float* __restrict__ W2,
    float* __restrict__ out)
{
    __shared__ unsigned short As[128 * 512];   // 128 KiB (one K-half of x)
    __shared__ float red[8][128];              // 4 KiB wave-private fold rows

    const int tid  = threadIdx.x;
    const int lane = tid & 63;
    const int wave = tid >> 6;      // 0..7
    const int rl   = lane & 31;
    const int half = lane >> 5;

    const int strip = blockIdx.x >> 1;          // 0..127
    const int mhalf = blockIdx.x & 1;           // hidden half (adjacent bids share x)
    const int row0  = strip * 128;

    // zero the fold accumulator (covered by the first staging barrier)
    ((float*)red)[tid]       = 0.f;
    ((float*)red)[tid + 512] = 0.f;

    // staging decomposition: wave w covers rows {j*8 + w}, lane covers col-slot
    const int so = lane;            // slot 0..63 (8 cols each)
    const int rb = wave;            // 0..7

#define STAGE_X(KSEL)                                                          \
    {                                                                          \
        const float* xsrc = xf + (size_t)row0 * D_IN + (KSEL) * 512 + so * 8;  \
        _Pragma("unroll")                                                      \
        for (int j = 0; j < 16; ++j) {                                         \
            const int r = j * 8 + rb;                                          \
            const float* p = xsrc + (size_t)r * D_IN;                          \
            float4 v0 = *(const float4*)(p);                                   \
            float4 v1 = *(const float4*)(p + 4);                               \
            uint4 o;                                                           \
            o.x = f2bf(v0.x) | (f2bf(v0.y) << 16);                             \
            o.y = f2bf(v0.z) | (f2bf(v0.w) << 16);                             \
            o.z = f2bf(v1.x) | (f2bf(v1.y) << 16);                             \
            o.w = f2bf(v1.z) | (f2bf(v1.w) << 16);                             \
            *(uint4*)(&As[r * 512 + ((so ^ (r & 31)) << 3)]) = o;              \
        }                                                                      \
    }

    STAGE_X(0);
    __syncthreads();
    int curtile = 0;

    // per-thread LDS byte bases for the 4 row-tiles (rows ti*32 + rl)
    const int ab0 = (0 * 32 + rl) * 1024;
    const int ab1 = (1 * 32 + rl) * 1024;
    const int ab2 = (2 * 32 + rl) * 1024;
    const int ab3 = (3 * 32 + rl) * 1024;

    // ---- main: 4 col-passes x 2 zigzagged K-halves ----
    for (int pass = 0; pass < 4; ++pass) {
        const int n0 = mhalf * 2048 + pass * 512 + wave * 64;
        const float w2a = W2[n0 + rl],      b0a = b0[n0 + rl];
        const float w2b = W2[n0 + 32 + rl], b0b = b0[n0 + 32 + rl];
        const int n32 = n0 >> 5;
        const unsigned short* w0p = wb + (size_t)n32 * 32768 + half * 256 + rl * 8;

        f32x16 acc[4][2] = {};

        for (int seg = 0; seg < 2; ++seg) {
            const int ksel = (pass & 1) ? (1 - seg) : seg;   // zigzag
            if (ksel != curtile) {
                __syncthreads();            // all waves done reading old tile
                STAGE_X(ksel);
                __syncthreads();
                curtile = ksel;
            }
            const unsigned short* ws0 = w0p + (size_t)(ksel * 32) * 512;
            const unsigned short* ws1 = ws0 + 32768;

            bf16x8 wf0[4], wf1[4];
#pragma unroll
            for (int p = 0; p < 4; ++p) {           // distance-4 register ring
                wf0[p] = *(const bf16x8*)(ws0 + p * 512);
                wf1[p] = *(const bf16x8*)(ws1 + p * 512);
            }

            const char* Ab = (const char*)As;
#pragma unroll 4
            for (int kk = 0; kk < 28; ++kk) {
                const int cur = kk & 3;
                const int off = (((kk * 2 + half) ^ rl) << 4);
                bf16x8 af0 = *(const bf16x8*)(Ab + ab0 + off);
                bf16x8 af1 = *(const bf16x8*)(Ab + ab1 + off);
                bf16x8 af2 = *(const bf16x8*)(Ab + ab2 + off);
                bf16x8 af3 = *(const bf16x8*)(Ab + ab3 + off);
                bf16x8 w0c = wf0[cur], w1c = wf1[cur];
                wf0[cur] = *(const bf16x8*)(ws0 + (kk + 4) * 512);
                wf1[cur] = *(const bf16x8*)(ws1 + (kk + 4) * 512);
                acc[0][0] = __builtin_amdgcn_mfma_f32_32x32x16_bf16(af0, w0c, acc[0][0], 0, 0, 0);
                acc[0][1] = __builtin_amdgcn_mfma_f32_32x32x16_bf16(af0, w1c, acc[0][1], 0, 0, 0);
                acc[1][0] = __builtin_amdgcn_mfma_f32_32x32x16_bf16(af1, w0c, acc[1][0], 0, 0, 0);
                acc[1][1] = __builtin_amdgcn_mfma_f32_32x32x16_bf16(af1, w1c, acc[1][1], 0, 0, 0);
                acc[2][0] = __builtin_amdgcn_mfma_f32_32x32x16_bf16(af2, w0c, acc[2][0], 0, 0, 0);
                acc[2][1] = __builtin_amdgcn_mfma_f32_32x32x16_bf16(af2, w1c, acc[2][1], 0, 0, 0);
                acc[3][0] = __builtin_amdgcn_mfma_f32_32x32x16_bf16(af3, w0c, acc[3][0], 0, 0, 0);
                acc[3][1] = __builtin_amdgcn_mfma_f32_32x32x16_bf16(af3, w1c, acc[3][1], 0, 0, 0);
            }
            // tail: consume the last 4 ring entries, no prefetch
#pragma unroll
            for (int kk = 28; kk < 32; ++kk) {
                const int cur = kk & 3;
                const int off = (((kk * 2 + half) ^ rl) << 4);
                bf16x8 af0 = *(const bf16x8*)(Ab + ab0 + off);
                bf16x8 af1 = *(const bf16x8*)(Ab + ab1 + off);
                bf16x8 af2 = *(const bf16x8*)(Ab + ab2 + off);
                bf16x8 af3 = *(const bf16x8*)(Ab + ab3 + off);
                acc[0][0] = __builtin_amdgcn_mfma_f32_32x32x16_bf16(af0, wf0[cur], acc[0][0], 0, 0, 0);
                acc[0][1] = __builtin_amdgcn_mfma_f32_32x32x16_bf16(af0, wf1[cur], acc[0][1], 0, 0, 0);
                acc[1][0] = __builtin_amdgcn_mfma_f32_32x32x16_bf16(af1, wf0[cur], acc[1][0], 0, 0, 0);
                acc[1][1] = __builtin_amdgcn_mfma_f32_32x32x16_bf16(af1, wf1[cur], acc[1][1], 0, 0, 0);
                acc[2][0] = __builtin_amdgcn_mfma_f32_32x32x16_bf16(af2, wf0[cur], acc[2][0], 0, 0, 0);
                acc[2][1] = __builtin_amdgcn_mfma_f32_32x32x16_bf16(af2, wf1[cur], acc[2][1], 0, 0, 0);
                acc[3][0] = __builtin_amdgcn_mfma_f32_32x32x16_bf16(af3, wf0[cur], acc[3][0], 0, 0, 0);
                acc[3][1] = __builtin_amdgcn_mfma_f32_32x32x16_bf16(af3, wf1[cur], acc[3][1], 0, 0, 0);
            }
        }

        // fold this pass: relu(h + b0) dot W2, shuffle-reduce the 32 col-lanes,
        // accumulate into this wave's private LDS rows (no cross-wave races).
        // C/D layout (m74/m101): col = lane&31, row = (r&3) + 8*(r>>2) + 4*half
#pragma unroll
        for (int ti = 0; ti < 4; ++ti)
#pragma unroll
            for (int r = 0; r < 16; ++r) {
                float p = fmaxf(acc[ti][0][r] + b0a, 0.f) * w2a
                        + fmaxf(acc[ti][1][r] + b0b, 0.f) * w2b;
#pragma unroll
                for (int m = 1; m <= 16; m <<= 1)
                    p += __shfl_xor(p, m, 64);        // stays within each 32-half
                if (rl == 0)
                    red[wave][ti * 32 + (r & 3) + 8 * (r >> 2) + 4 * half] += p;
            }
    }

    __syncthreads();
    if (tid < 128) {
        float s = 0.f;
#pragma unroll
        for (int w = 0; w < 8; ++w) s += red[w][tid];
        atomicAdd(&out[row0 + tid], s);               // 2 adds/row (hidden halves)
    }
#undef STAGE_X
}

// ---------------- naive fallback (correctness only; ws too small) ------------
__global__ __launch_bounds__(256) void k_naive(
    const float* __restrict__ x, const float* __restrict__ W0,
    const float* __restrict__ b0, const float* __restrict__ A,
    const float* __restrict__ Bl, const float* __restrict__ W2,
    const float* __restrict__ b2, float* __restrict__ out)
{
    __shared__ float xs[D_IN];
    int b = blockIdx.x;
    for (int d = threadIdx.x; d < D_IN; d += 256) xs[d] = x[(size_t)b * D_IN + d];
    __syncthreads();
    float part = 0.f;
    for (int m = threadIdx.x; m < M_HID; m += 256) {
        float h = b0[m];
        const float* wr = W0 + (size_t)m * D_IN;
        const float* brow = Bl + m * R_LORA;
        for (int d = 0; d < D_IN; ++d) {
            float w = wr[d];
            for (int r = 0; r < R_LORA; ++r) w += SCALING * brow[r] * A[r * D_IN + d];
            h += xs[d] * w;
        }
        part += fmaxf(h, 0.f) * W2[m];
    }
    __shared__ float sred[256];
    sred[threadIdx.x] = part;
    __syncthreads();
    for (int s = 128; s > 0; s >>= 1) {
        if (threadIdx.x < s) sred[threadIdx.x] += sred[threadIdx.x + s];
        __syncthreads();
    }
    if (threadIdx.x == 0) out[b] = sred[0] + b2[0];
}

// ---------------- host ----------------
extern "C" void kernel_launch(void* const* d_in, const int* in_sizes, int n_in,
                              void* d_out, int out_size, void* d_ws, size_t ws_size,
                              hipStream_t stream) {
    const float* x  = (const float*)d_in[0];
    const float* W0 = (const float*)d_in[1];
    const float* b0 = (const float*)d_in[2];
    const float* A  = (const float*)d_in[3];
    const float* Bl = (const float*)d_in[4];
    const float* W2 = (const float*)d_in[5];
    const float* b2 = (const float*)d_in[6];
    float* out = (float*)d_out;

    const size_t wb_bytes = (size_t)M_HID * D_IN * 2;   // 8 MiB fragment-ordered W_eff
    if (ws_size >= wb_bytes) {
        unsigned short* wb = (unsigned short*)d_ws;
        hipLaunchKernelGGL(k_wprep, dim3(M_HID / 32 * 2), dim3(512), 0, stream,
                           W0, A, Bl, b2, wb, out);
        hipLaunchKernelGGL(k_strip, dim3(BATCH / 128 * 2), dim3(512), 0, stream,
                           x, wb, b0, W2, out);
    } else {
        hipLaunchKernelGGL(k_naive, dim3(BATCH), dim3(256), 0, stream,
                           x, W0, b0, A, Bl, W2, b2, out);
    }
}

// Round 7
// 315.804 us; speedup vs baseline: 1.1242x; 1.1242x over previous
//
#include <hip/hip_runtime.h>
#include <hip/hip_bf16.h>
#include <stdint.h>

// Problem constants (fixed by the reference setup_inputs)
#define BATCH  16384
#define D_IN   1024
#define M_HID  4096
#define R_LORA 16
#define SCALING 2.0f   // ALPHA/R = 32/16

// R12 consolidation: three structural rewrites (R8 XCD-halves, R10 XCD-quarter
// queues, R11 128-row K-zigzag) all regressed k_strip vs the proven 147us R5
// body -- per-CU wf-byte amortization keeps costing more in staging/spill than
// it saves. Meanwhile the ~100us gap between total (250us) and k_strip (147us)
// was never attacked WITH the fast strip: it is k_wprep v1's uncoalesced W0
// reads (4KB lane stride, ~4x line amplification, latency-bound). R12 ships:
//   (1) k_strip = Round-0 body VERBATIM (measured 147-159us, 92 VGPR, no
//       spill; staging-phase bank conflicts are one-time and benign).
//   (2) k_wprep v3 (R10/R11-proven, bit-identical wb): coalesced W0/A reads,
//       B pre-scaled in LDS, scattered 16B writes. Floor ~10-20us vs ~100.
// Clean attribution: any total delta vs R0's 250us is wprep's alone.

#define STRIP    64
#define NTHREADS 512

typedef __bf16 bf16x8 __attribute__((ext_vector_type(8)));
typedef float  f32x16 __attribute__((ext_vector_type(16)));

__device__ __forceinline__ unsigned f2bf(float f) {
    union { float f; unsigned u; } c; c.f = f;
    unsigned u = c.u;
    return ((u + 0x7FFFu + ((u >> 16) & 1u)) >> 16);
}

// ---------------- prep v3: W_eff -> fragment-ordered bf16 ----------------
// Layout (shorts): n32*32768 + c*256 + rl*8 holds W_eff[n32*32+rl][c*8 .. c*8+8).
// Block = one n32 x one col-half. W0 reads: 64 lanes x 32B contiguous per row
// (coalesced). A reads coalesced (64KB, L2-resident). B pre-scaled into LDS.
// Writes: 16B chunks at 512B stride (fire-and-forget, no read stall).
__global__ __launch_bounds__(512) void k_wprep(
    const float* __restrict__ W0, const float* __restrict__ A,
    const float* __restrict__ Bl, unsigned short* __restrict__ wb)
{
    __shared__ float Bs[512];                     // 32 rows x 16 r, pre-scaled
    const int tid   = threadIdx.x;
    const int n32   = blockIdx.x >> 1;            // 0..127
    const int chalf = blockIdx.x & 1;
    const int col0  = chalf * 512;

    Bs[tid] = SCALING * Bl[n32 * 512 + tid];
    __syncthreads();

    const int lane = tid & 63;
    const int w    = tid >> 6;                    // 0..7
    const float* a_base = A + col0 + lane * 8;

#pragma unroll
    for (int j = 0; j < 4; ++j) {
        const int row = j * 8 + w;                // 0..31
        const int n   = n32 * 32 + row;
        const float* p = W0 + (size_t)n * D_IN + col0 + lane * 8;
        float4 v0 = *(const float4*)(p);
        float4 v1 = *(const float4*)(p + 4);
        const float* bsr = &Bs[row * 16];
#pragma unroll
        for (int r = 0; r < R_LORA; ++r) {
            float s = bsr[r];
            const float* ap = a_base + r * D_IN;
            float4 a0 = *(const float4*)(ap);
            float4 a1 = *(const float4*)(ap + 4);
            v0.x += s * a0.x; v0.y += s * a0.y; v0.z += s * a0.z; v0.w += s * a0.w;
            v1.x += s * a1.x; v1.y += s * a1.y; v1.z += s * a1.z; v1.w += s * a1.w;
        }
        uint4 o;
        o.x = f2bf(v0.x) | (f2bf(v0.y) << 16);
        o.y = f2bf(v0.z) | (f2bf(v0.w) << 16);
        o.z = f2bf(v1.x) | (f2bf(v1.y) << 16);
        o.w = f2bf(v1.z) | (f2bf(v1.w) << 16);
        *(uint4*)(&wb[(size_t)n32 * 32768 + (size_t)(chalf * 64 + lane) * 256 + row * 8]) = o;
    }
}

// ---------------- main fused kernel (Round-0 body, measured 147-159us) --------
__global__ __launch_bounds__(NTHREADS, 2) void k_strip(
    const float* __restrict__ xf, const unsigned short* __restrict__ wb,
    const float* __restrict__ b0, const float* __restrict__ W2,
    const float* __restrict__ b2, float* __restrict__ out)
{
    // x strip, chunk-major: As[c*512 + r*8 + j] = x_bf16[row0+r][c*8+j]
    __shared__ unsigned short As[STRIP * D_IN];   // 128 KiB
    __shared__ float red[8][STRIP];               // 2 KiB cross-wave reduce

    const int tid  = threadIdx.x;
    const int lane = tid & 63;
    const int wave = tid >> 6;
    const int rl   = lane & 31;
    const int half = lane >> 5;
    const int row0 = blockIdx.x * STRIP;

    // ---- phase 1: x fp32 -> bf16 into resident LDS strip (coalesced reads;
    //      8-way LDS write conflicts are one-time, off the critical path) ----
    {
        const int r  = tid >> 3;                  // 0..63
        const int c0 = tid & 7;
        const float* xr = xf + (size_t)(row0 + r) * D_IN;
#pragma unroll
        for (int i = 0; i < 16; ++i) {
            int c = i * 8 + c0;
            float4 v0 = *(const float4*)(xr + c * 8);
            float4 v1 = *(const float4*)(xr + c * 8 + 4);
            uint4 o;
            o.x = f2bf(v0.x) | (f2bf(v0.y) << 16);
            o.y = f2bf(v0.z) | (f2bf(v0.w) << 16);
            o.z = f2bf(v1.x) | (f2bf(v1.y) << 16);
            o.w = f2bf(v1.z) | (f2bf(v1.w) << 16);
            *(uint4*)(&As[c * 512 + r * 8]) = o;
        }
    }
    __syncthreads();   // the only barrier before the final reduce

    float rowpart[2][16];
#pragma unroll
    for (int ti = 0; ti < 2; ++ti)
#pragma unroll
        for (int r = 0; r < 16; ++r) rowpart[ti][r] = 0.f;

    // ---- main: 8 passes x (K-loop with zero barriers) ----
    for (int pass = 0; pass < 8; ++pass) {
        const int n0 = wave * 64 + pass * 512;
        const float w2a = W2[n0 + rl],      b0a = b0[n0 + rl];
        const float w2b = W2[n0 + 32 + rl], b0b = b0[n0 + 32 + rl];
        const int n32 = wave * 2 + pass * 16;
        const unsigned short* w0p = wb + (size_t)n32 * 32768 + half * 256 + rl * 8;
        const unsigned short* w1p = w0p + 32768;

        f32x16 acc[2][2] = {};
        bf16x8 wf0[4], wf1[4];
#pragma unroll
        for (int p = 0; p < 4; ++p) {             // distance-4 register prefetch
            wf0[p] = *(const bf16x8*)(w0p + p * 512);
            wf1[p] = *(const bf16x8*)(w1p + p * 512);
        }

#pragma unroll 4
        for (int kk = 0; kk < 64; ++kk) {
            const int cur = kk & 3;
            const int coff = (kk * 2 + half) * 512 + rl * 8;
            bf16x8 af0 = *(const bf16x8*)(&As[coff]);        // rows 0..31
            bf16x8 af1 = *(const bf16x8*)(&As[coff + 256]);  // rows 32..63
            bf16x8 w0c = wf0[cur], w1c = wf1[cur];
            if (kk < 60) {
                wf0[cur] = *(const bf16x8*)(w0p + (kk + 4) * 512);
                wf1[cur] = *(const bf16x8*)(w1p + (kk + 4) * 512);
            }
            acc[0][0] = __builtin_amdgcn_mfma_f32_32x32x16_bf16(af0, w0c, acc[0][0], 0, 0, 0);
            acc[0][1] = __builtin_amdgcn_mfma_f32_32x32x16_bf16(af0, w1c, acc[0][1], 0, 0, 0);
            acc[1][0] = __builtin_amdgcn_mfma_f32_32x32x16_bf16(af1, w0c, acc[1][0], 0, 0, 0);
            acc[1][1] = __builtin_amdgcn_mfma_f32_32x32x16_bf16(af1, w1c, acc[1][1], 0, 0, 0);
        }

        // fold this pass: relu(h + bias) dot W2, accumulate per-lane
#pragma unroll
        for (int ti = 0; ti < 2; ++ti)
#pragma unroll
            for (int r = 0; r < 16; ++r)
                rowpart[ti][r] += fmaxf(acc[ti][0][r] + b0a, 0.f) * w2a
                                + fmaxf(acc[ti][1][r] + b0b, 0.f) * w2b;
    }

    // ---- final: shuffle-reduce over 32 col-lanes, cross-wave sum via LDS ----
    // C/D layout (m74/m101): col = lane&31, row = (r&3) + 8*(r>>2) + 4*half
#pragma unroll
    for (int ti = 0; ti < 2; ++ti)
#pragma unroll
        for (int r = 0; r < 16; ++r) {
            float p = rowpart[ti][r];
#pragma unroll
            for (int m = 1; m <= 16; m <<= 1)
                p += __shfl_xor(p, m, 64);        // stays within each 32-half
            if (rl == 0)
                red[wave][ti * 32 + (r & 3) + 8 * (r >> 2) + 4 * half] = p;
        }
    __syncthreads();
    if (tid < STRIP) {
        float s = b2[0];
#pragma unroll
        for (int w = 0; w < 8; ++w) s += red[w][tid];
        out[row0 + tid] = s;
    }
}

// ---------------- naive fallback (correctness only; ws too small) ----------------
__global__ __launch_bounds__(256) void k_naive(
    const float* __restrict__ x, const float* __restrict__ W0,
    const float* __restrict__ b0, const float* __restrict__ A,
    const float* __restrict__ Bl, const float* __restrict__ W2,
    const float* __restrict__ b2, float* __restrict__ out)
{
    __shared__ float xs[D_IN];
    int b = blockIdx.x;
    for (int d = threadIdx.x; d < D_IN; d += 256) xs[d] = x[(size_t)b * D_IN + d];
    __syncthreads();
    float part = 0.f;
    for (int m = threadIdx.x; m < M_HID; m += 256) {
        float h = b0[m];
        const float* wr = W0 + (size_t)m * D_IN;
        const float* brow = Bl + m * R_LORA;
        for (int d = 0; d < D_IN; ++d) {
            float w = wr[d];
            for (int r = 0; r < R_LORA; ++r) w += SCALING * brow[r] * A[r * D_IN + d];
            h += xs[d] * w;
        }
        part += fmaxf(h, 0.f) * W2[m];
    }
    __shared__ float sred[256];
    sred[threadIdx.x] = part;
    __syncthreads();
    for (int s = 128; s > 0; s >>= 1) {
        if (threadIdx.x < s) sred[threadIdx.x] += sred[threadIdx.x + s];
        __syncthreads();
    }
    if (threadIdx.x == 0) out[b] = sred[0] + b2[0];
}

// ---------------- host ----------------
extern "C" void kernel_launch(void* const* d_in, const int* in_sizes, int n_in,
                              void* d_out, int out_size, void* d_ws, size_t ws_size,
                              hipStream_t stream) {
    const float* x  = (const float*)d_in[0];
    const float* W0 = (const float*)d_in[1];
    const float* b0 = (const float*)d_in[2];
    const float* A  = (const float*)d_in[3];
    const float* Bl = (const float*)d_in[4];
    const float* W2 = (const float*)d_in[5];
    const float* b2 = (const float*)d_in[6];
    float* out = (float*)d_out;

    const size_t wb_bytes = (size_t)M_HID * D_IN * 2;   // 8 MiB fragment-ordered W_eff
    if (ws_size >= wb_bytes) {
        unsigned short* wb = (unsigned short*)d_ws;
        hipLaunchKernelGGL(k_wprep, dim3(M_HID / 32 * 2), dim3(512), 0, stream,
                           W0, A, Bl, wb);
        hipLaunchKernelGGL(k_strip, dim3(BATCH / STRIP), dim3(NTHREADS), 0, stream,
                           x, wb, b0, W2, b2, out);
    } else {
        hipLaunchKernelGGL(k_naive, dim3(BATCH), dim3(256), 0, stream,
                           x, W0, b0, A, Bl, W2, b2, out);
    }
}

// Round 8
// 245.112 us; speedup vs baseline: 1.4485x; 1.2884x over previous
//
#include <hip/hip_runtime.h>
#include <hip/hip_bf16.h>
#include <stdint.h>

// Problem constants (fixed by the reference setup_inputs)
#define BATCH  16384
#define D_IN   1024
#define M_HID  4096
#define R_LORA 16
#define SCALING 2.0f   // ALPHA/R = 32/16

// R13: residue ledger across R0-R12 resolves the ~100-160us non-strip time as
// k_wprep itself: v1 (scattered reads) ~95-102us, v3 (scattered 16B writes)
// ~130-160us -- both ~5-10x above the ~15us I/O floor. The wb fragment layout
// is a transpose, so one global side always scatters UNLESS the transpose
// goes through LDS. wprep v4: coalesced W0 reads (2KB/wave-row) -> per-thread
// 8x8 patch with A from LDS (conflict-free [r][h][lane] f4 layout, B
// pre-scaled) -> bf16 pack into 32KB LDS tile with XOR swizzle row^(l&7)
// (store AND readback at the 8-lane/4-bank-group optimum) -> linear copy-out
// (LDS-linear == global-fragment-linear for the block) = coalesced 4KB/wave
// stores. k_strip is the proven R0/R12 body VERBATIM (155us, 92 VGPR).
// Attribution stays clean: any total delta vs R12's 316us is wprep's alone.

#define STRIP    64
#define NTHREADS 512

typedef __bf16 bf16x8 __attribute__((ext_vector_type(8)));
typedef float  f32x16 __attribute__((ext_vector_type(16)));

__device__ __forceinline__ unsigned f2bf(float f) {
    union { float f; unsigned u; } c; c.f = f;
    unsigned u = c.u;
    return ((u + 0x7FFFu + ((u >> 16) & 1u)) >> 16);
}

// ---------------- prep v4: W_eff -> fragment-ordered bf16, LDS transpose ------
// Global layout (shorts): n32*32768 + c*256 + rl*8 + j = W_eff[n32*32+rl][c*8+j]
// Block = (n32, chalf): rows n32*32..+32, cols chalf*512..+512.
// Output region = shorts [n32*32768 + chalf*16384, +16384) -- contiguous 32 KB.
__global__ __launch_bounds__(256) void k_wprep(
    const float* __restrict__ W0, const float* __restrict__ A,
    const float* __restrict__ Bl, unsigned short* __restrict__ wb)
{
    __shared__ float A4[8192];                 // 32 KiB: [r][h][lane] float4s
    __shared__ float Bs[512];                  // 32 rows x 16 r, pre-scaled
    __shared__ unsigned short floc[16384];     // 32 KiB bf16 tile, XOR-swizzled

    const int tid   = threadIdx.x;             // 256 threads
    const int n32   = blockIdx.x >> 1;         // 0..127
    const int chalf = blockIdx.x & 1;
    const int col0  = chalf * 512;

    // ---- stage A-half + pre-scaled B into LDS ----
    {
        const float4* Asrc = (const float4*)A;
#pragma unroll
        for (int i = 0; i < 8; ++i) {
            int idx = i * 256 + tid;           // float4-linear: r*128 + h*64 + l
            int r = idx >> 7, h = (idx >> 6) & 1, ll = idx & 63;
            ((float4*)A4)[idx] = Asrc[r * 256 + (col0 >> 2) + ll * 2 + h];
        }
        Bs[tid]       = SCALING * Bl[n32 * 512 + tid];
        Bs[tid + 256] = SCALING * Bl[n32 * 512 + 256 + tid];
    }
    __syncthreads();

    const int w = tid >> 6;                    // wave 0..3 -> rows w*8..w*8+7
    const int l = tid & 63;                    // col octet within the half

    // ---- compute 8x8 W_eff patch; W0 reads coalesced (2 KB per wave-row) ----
    float acc[8][8];
#pragma unroll
    for (int jj = 0; jj < 8; ++jj) {
        const int row = w * 8 + jj;
        const float* p = W0 + (size_t)(n32 * 32 + row) * D_IN + col0 + l * 8;
        float4 v0 = *(const float4*)(p);
        float4 v1 = *(const float4*)(p + 4);
        acc[jj][0] = v0.x; acc[jj][1] = v0.y; acc[jj][2] = v0.z; acc[jj][3] = v0.w;
        acc[jj][4] = v1.x; acc[jj][5] = v1.y; acc[jj][6] = v1.z; acc[jj][7] = v1.w;
    }
#pragma unroll
    for (int r = 0; r < R_LORA; ++r) {
        float4 a0 = ((const float4*)A4)[r * 128 + l];        // conflict-free
        float4 a1 = ((const float4*)A4)[r * 128 + 64 + l];
        const float av[8] = { a0.x, a0.y, a0.z, a0.w, a1.x, a1.y, a1.z, a1.w };
#pragma unroll
        for (int jj = 0; jj < 8; ++jj) {
            float s = Bs[(w * 8 + jj) * 16 + r];             // wave-uniform bcast
#pragma unroll
            for (int k = 0; k < 8; ++k) acc[jj][k] += s * av[k];
        }
    }

    // ---- pack bf16, store into floc with XOR swizzle (conflict-free) ----
#pragma unroll
    for (int jj = 0; jj < 8; ++jj) {
        const int row = w * 8 + jj;
        uint4 o;
        o.x = f2bf(acc[jj][0]) | (f2bf(acc[jj][1]) << 16);
        o.y = f2bf(acc[jj][2]) | (f2bf(acc[jj][3]) << 16);
        o.z = f2bf(acc[jj][4]) | (f2bf(acc[jj][5]) << 16);
        o.w = f2bf(acc[jj][6]) | (f2bf(acc[jj][7]) << 16);
        *(uint4*)((char*)floc + l * 512 + ((row ^ (l & 7)) << 4)) = o;
    }
    __syncthreads();

    // ---- linear copy-out: LDS-linear == global-fragment-linear; 4 KB/wave ----
    unsigned short* gdst = wb + (size_t)n32 * 32768 + chalf * 16384;
#pragma unroll
    for (int i = 0; i < 8; ++i) {
        int L16 = i * 256 + tid;               // 16-byte unit index
        int ll = L16 >> 5, rr = L16 & 31;      // byte = ll*512 + rr*16 (linear)
        uint4 v = *(const uint4*)((const char*)floc + ll * 512 + ((rr ^ (ll & 7)) << 4));
        *(uint4*)(gdst + (size_t)L16 * 8) = v;
    }
}

// ---------------- main fused kernel (Round-0 body, measured 147-158us) --------
__global__ __launch_bounds__(NTHREADS, 2) void k_strip(
    const float* __restrict__ xf, const unsigned short* __restrict__ wb,
    const float* __restrict__ b0, const float* __restrict__ W2,
    const float* __restrict__ b2, float* __restrict__ out)
{
    // x strip, chunk-major: As[c*512 + r*8 + j] = x_bf16[row0+r][c*8+j]
    __shared__ unsigned short As[STRIP * D_IN];   // 128 KiB
    __shared__ float red[8][STRIP];               // 2 KiB cross-wave reduce

    const int tid  = threadIdx.x;
    const int lane = tid & 63;
    const int wave = tid >> 6;
    const int rl   = lane & 31;
    const int half = lane >> 5;
    const int row0 = blockIdx.x * STRIP;

    // ---- phase 1: x fp32 -> bf16 into resident LDS strip (coalesced reads;
    //      8-way LDS write conflicts are one-time, off the critical path) ----
    {
        const int r  = tid >> 3;                  // 0..63
        const int c0 = tid & 7;
        const float* xr = xf + (size_t)(row0 + r) * D_IN;
#pragma unroll
        for (int i = 0; i < 16; ++i) {
            int c = i * 8 + c0;
            float4 v0 = *(const float4*)(xr + c * 8);
            float4 v1 = *(const float4*)(xr + c * 8 + 4);
            uint4 o;
            o.x = f2bf(v0.x) | (f2bf(v0.y) << 16);
            o.y = f2bf(v0.z) | (f2bf(v0.w) << 16);
            o.z = f2bf(v1.x) | (f2bf(v1.y) << 16);
            o.w = f2bf(v1.z) | (f2bf(v1.w) << 16);
            *(uint4*)(&As[c * 512 + r * 8]) = o;
        }
    }
    __syncthreads();   // the only barrier before the final reduce

    float rowpart[2][16];
#pragma unroll
    for (int ti = 0; ti < 2; ++ti)
#pragma unroll
        for (int r = 0; r < 16; ++r) rowpart[ti][r] = 0.f;

    // ---- main: 8 passes x (K-loop with zero barriers) ----
    for (int pass = 0; pass < 8; ++pass) {
        const int n0 = wave * 64 + pass * 512;
        const float w2a = W2[n0 + rl],      b0a = b0[n0 + rl];
        const float w2b = W2[n0 + 32 + rl], b0b = b0[n0 + 32 + rl];
        const int n32 = wave * 2 + pass * 16;
        const unsigned short* w0p = wb + (size_t)n32 * 32768 + half * 256 + rl * 8;
        const unsigned short* w1p = w0p + 32768;

        f32x16 acc[2][2] = {};
        bf16x8 wf0[4], wf1[4];
#pragma unroll
        for (int p = 0; p < 4; ++p) {             // distance-4 register prefetch
            wf0[p] = *(const bf16x8*)(w0p + p * 512);
            wf1[p] = *(const bf16x8*)(w1p + p * 512);
        }

#pragma unroll 4
        for (int kk = 0; kk < 64; ++kk) {
            const int cur = kk & 3;
            const int coff = (kk * 2 + half) * 512 + rl * 8;
            bf16x8 af0 = *(const bf16x8*)(&As[coff]);        // rows 0..31
            bf16x8 af1 = *(const bf16x8*)(&As[coff + 256]);  // rows 32..63
            bf16x8 w0c = wf0[cur], w1c = wf1[cur];
            if (kk < 60) {
                wf0[cur] = *(const bf16x8*)(w0p + (kk + 4) * 512);
                wf1[cur] = *(const bf16x8*)(w1p + (kk + 4) * 512);
            }
            acc[0][0] = __builtin_amdgcn_mfma_f32_32x32x16_bf16(af0, w0c, acc[0][0], 0, 0, 0);
            acc[0][1] = __builtin_amdgcn_mfma_f32_32x32x16_bf16(af0, w1c, acc[0][1], 0, 0, 0);
            acc[1][0] = __builtin_amdgcn_mfma_f32_32x32x16_bf16(af1, w0c, acc[1][0], 0, 0, 0);
            acc[1][1] = __builtin_amdgcn_mfma_f32_32x32x16_bf16(af1, w1c, acc[1][1], 0, 0, 0);
        }

        // fold this pass: relu(h + bias) dot W2, accumulate per-lane
#pragma unroll
        for (int ti = 0; ti < 2; ++ti)
#pragma unroll
            for (int r = 0; r < 16; ++r)
                rowpart[ti][r] += fmaxf(acc[ti][0][r] + b0a, 0.f) * w2a
                                + fmaxf(acc[ti][1][r] + b0b, 0.f) * w2b;
    }

    // ---- final: shuffle-reduce over 32 col-lanes, cross-wave sum via LDS ----
    // C/D layout (m74/m101): col = lane&31, row = (r&3) + 8*(r>>2) + 4*half
#pragma unroll
    for (int ti = 0; ti < 2; ++ti)
#pragma unroll
        for (int r = 0; r < 16; ++r) {
            float p = rowpart[ti][r];
#pragma unroll
            for (int m = 1; m <= 16; m <<= 1)
                p += __shfl_xor(p, m, 64);        // stays within each 32-half
            if (rl == 0)
                red[wave][ti * 32 + (r & 3) + 8 * (r >> 2) + 4 * half] = p;
        }
    __syncthreads();
    if (tid < STRIP) {
        float s = b2[0];
#pragma unroll
        for (int w = 0; w < 8; ++w) s += red[w][tid];
        out[row0 + tid] = s;
    }
}

// ---------------- naive fallback (correctness only; ws too small) ----------------
__global__ __launch_bounds__(256) void k_naive(
    const float* __restrict__ x, const float* __restrict__ W0,
    const float* __restrict__ b0, const float* __restrict__ A,
    const float* __restrict__ Bl, const float* __restrict__ W2,
    const float* __restrict__ b2, float* __restrict__ out)
{
    __shared__ float xs[D_IN];
    int b = blockIdx.x;
    for (int d = threadIdx.x; d < D_IN; d += 256) xs[d] = x[(size_t)b * D_IN + d];
    __syncthreads();
    float part = 0.f;
    for (int m = threadIdx.x; m < M_HID; m += 256) {
        float h = b0[m];
        const float* wr = W0 + (size_t)m * D_IN;
        const float* brow = Bl + m * R_LORA;
        for (int d = 0; d < D_IN; ++d) {
            float w = wr[d];
            for (int r = 0; r < R_LORA; ++r) w += SCALING * brow[r] * A[r * D_IN + d];
            h += xs[d] * w;
        }
        part += fmaxf(h, 0.f) * W2[m];
    }
    __shared__ float sred[256];
    sred[threadIdx.x] = part;
    __syncthreads();
    for (int s = 128; s > 0; s >>= 1) {
        if (threadIdx.x < s) sred[threadIdx.x] += sred[threadIdx.x + s];
        __syncthreads();
    }
    if (threadIdx.x == 0) out[b] = sred[0] + b2[0];
}

// ---------------- host ----------------
extern "C" void kernel_launch(void* const* d_in, const int* in_sizes, int n_in,
                              void* d_out, int out_size, void* d_ws, size_t ws_size,
                              hipStream_t stream) {
    const float* x  = (const float*)d_in[0];
    const float* W0 = (const float*)d_in[1];
    const float* b0 = (const float*)d_in[2];
    const float* A  = (const float*)d_in[3];
    const float* Bl = (const float*)d_in[4];
    const float* W2 = (const float*)d_in[5];
    const float* b2 = (const float*)d_in[6];
    float* out = (float*)d_out;

    const size_t wb_bytes = (size_t)M_HID * D_IN * 2;   // 8 MiB fragment-ordered W_eff
    if (ws_size >= wb_bytes) {
        unsigned short* wb = (unsigned short*)d_ws;
        hipLaunchKernelGGL(k_wprep, dim3(256), dim3(256), 0, stream,
                           W0, A, Bl, wb);
        hipLaunchKernelGGL(k_strip, dim3(BATCH / STRIP), dim3(NTHREADS), 0, stream,
                           x, wb, b0, W2, b2, out);
    } else {
        hipLaunchKernelGGL(k_naive, dim3(BATCH), dim3(256), 0, stream,
                           x, W0, b0, A, Bl, W2, b2, out);
    }
}